// Round 3
// baseline (296.469 us; speedup 1.0000x reference)
//
#include <hip/hip_runtime.h>
#include <math.h>

// Problem constants
#define CC 3
#define HH 1280
#define WW 720
#define BSZ 20
#define NHB 64
#define NWB 36
#define NBLK (NHB*NWB)          // 2304
#define OUT_IMG (3*5120*2880)   // 44236800

// ---------------------------------------------------------------------------
// Light expert: per 20x20 block, zero-pad conv3x3 (3->48) + pixel_shuffle(4)
// + clamp[0,0.6]+0.4, folded directly into the [3][5120][2880] output.
// mask = sigmoid(..) > 1.0 is always False -> complex expert is dead code.
// One workgroup (256 thr) per block; thread computes one conv row (oc,h).
// ALL I/O IS FLOAT32 (reference is pure jnp.float32).
// ---------------------------------------------------------------------------
__global__ __launch_bounds__(256) void light_kernel(
    const float* __restrict__ inp,
    const float* __restrict__ wl,
    const float* __restrict__ bl,
    float* __restrict__ out) {
  __shared__ __align__(16) float in_s[3][22][24];  // zero-padded block, rows padded to 24
  __shared__ float w_s[48*27 + 48];
  const int l  = blockIdx.x;
  const int bi = l / NWB, bj = l % NWB;
  const int tid = threadIdx.x;

  for (int i = tid; i < 3*22*24; i += 256) ((float*)in_s)[i] = 0.0f;
  for (int i = tid; i < 48*27; i += 256) w_s[i] = wl[i];
  if (tid < 48) w_s[48*27 + tid] = bl[tid];
  __syncthreads();
  // stage 20x20x3 block; global float4 loads (WW=720 and 20*bj are mult of 4)
  for (int i = tid; i < 300; i += 256) {
    int x4 = i % 5; int r = (i / 5) % 20; int c = i / 100;
    const float4 v = *(const float4*)&inp[(c*HH + bi*BSZ + r)*WW + bj*BSZ + 4*x4];
    float* dst = &in_s[c][r+1][1 + 4*x4];
    dst[0] = v.x; dst[1] = v.y; dst[2] = v.z; dst[3] = v.w;
  }
  __syncthreads();

  const int row0 = bi * 80, col0 = bj * 80;
  for (int pair = tid; pair < 960; pair += 256) {
    int oc = pair % 48;
    int h  = pair / 48;
    float wr[27];
    #pragma unroll
    for (int j = 0; j < 27; ++j) wr[j] = w_s[oc*27 + j];
    float acc[20];
    float bias = w_s[48*27 + oc];
    #pragma unroll
    for (int w = 0; w < 20; ++w) acc[w] = bias;

    #pragma unroll
    for (int ic = 0; ic < 3; ++ic)
      #pragma unroll
      for (int ky = 0; ky < 3; ++ky) {
        const float* row = &in_s[ic][h + ky][0];
        float r[24];
        #pragma unroll
        for (int j = 0; j < 6; ++j) {
          float4 v = ((const float4*)row)[j];   // ds_read_b128
          r[j*4+0] = v.x; r[j*4+1] = v.y; r[j*4+2] = v.z; r[j*4+3] = v.w;
        }
        float w0 = wr[ic*9 + ky*3 + 0];
        float w1 = wr[ic*9 + ky*3 + 1];
        float w2 = wr[ic*9 + ky*3 + 2];
        #pragma unroll
        for (int w = 0; w < 20; ++w)
          acc[w] += r[w]*w0 + r[w+1]*w1 + r[w+2]*w2;
      }

    // pixel_shuffle(4): out[c][h*4+r1][w*4+r2] = y[c*16+r1*4+r2][h][w]
    int c  = oc >> 4;
    int r1 = (oc >> 2) & 3;
    int r2 = oc & 3;
    int gy = row0 + h*4 + r1;
    int base = (c*5120 + gy)*2880 + col0 + r2;
    #pragma unroll
    for (int w = 0; w < 20; ++w) {
      float v = fminf(fmaxf(acc[w], 0.0f), 0.6f) + 0.4f;
      out[base + w*4] = v;
    }
  }
}

// ---------------------------------------------------------------------------
// Fused gate CNN: one workgroup per gate output (2304 blocks), ZERO workspace.
//   stage A: conv1(3->16, edge-pad) + tanh + maxpool2 on a local 12x12 patch
//   stage B: conv2(16->8, edge-pad) + maxpool2 -> 8x5x5 window
//   stage C: 5x5x8 dot (conv3 stride 5) + sigmoid -> 1 scalar
// Edge-replicate padding is baked in via coordinate clamps (verified to match
// both edge_pad1 applications exactly).
// ---------------------------------------------------------------------------
__global__ __launch_bounds__(256) void gate_fused(
    const float* __restrict__ inp,
    const float* __restrict__ w1,
    const float* __restrict__ b1,
    const float* __restrict__ w2,
    const float* __restrict__ b2,
    const float* __restrict__ w3,
    const float* __restrict__ b3,
    float* __restrict__ cv) {
  __shared__ float ins[3][26][28];    // input patch, clamped coords (edge pad baked in)
  __shared__ float w1s[16*27];
  __shared__ float b1s[16];
  __shared__ float w2s[8*16*9];
  __shared__ float b2s[8];
  __shared__ float w3s[200];
  __shared__ float b3s;
  __shared__ float x1s[16][12][13];   // post-pool conv1 patch (cols padded 12->13)
  __shared__ float red[256];

  const int tid = threadIdx.x;
  const int l  = blockIdx.x;
  const int oy = l / NWB, ox = l % NWB;

  for (int i = tid; i < 16*27; i += 256) w1s[i] = w1[i];
  for (int i = tid; i < 8*16*9; i += 256) w2s[i] = w2[i];
  for (int i = tid; i < 200; i += 256) w3s[i] = w3[i];
  if (tid < 16) b1s[tid] = b1[tid];
  if (tid < 8)  b2s[tid] = b2[tid];
  if (tid == 0) b3s = b3[0];

  // input patch rows [20*oy-3, 20*oy+23), cols [20*ox-3, 20*ox+23), clamped
  for (int i = tid; i < 3*26*28; i += 256) {
    int b = i % 28; int a = (i / 28) % 26; int ic = i / (26*28);
    int gy = 20*oy - 3 + a; gy = gy < 0 ? 0 : (gy > HH-1 ? HH-1 : gy);
    int gx = 20*ox - 3 + b; gx = gx < 0 ? 0 : (gx > WW-1 ? WW-1 : gx);
    ins[ic][a][b] = inp[(ic*HH + gy)*WW + gx];
  }
  __syncthreads();

  // ---- stage A: x1s[oc][ly][lx] = tanh(maxpool2(conv1)) at x1p coords
  //      (10*oy-1+ly, 10*ox-1+lx), clamped (this bakes in conv2's edge pad)
  for (int v = tid; v < 16*12*12; v += 256) {
    int oc = v / 144; int rem = v - oc*144; int ly = rem / 12; int lx = rem - ly*12;
    int y1 = 10*oy - 1 + ly; y1 = y1 < 0 ? 0 : (y1 > 639 ? 639 : y1);
    int x1 = 10*ox - 1 + lx; x1 = x1 < 0 ? 0 : (x1 > 359 ? 359 : x1);
    int ry = 2*y1 + 2 - 20*oy;   // local row of conv input patch, in [0,22]
    int rx = 2*x1 + 2 - 20*ox;
    float patch[3][4][4];
    #pragma unroll
    for (int ic = 0; ic < 3; ++ic)
      #pragma unroll
      for (int d = 0; d < 4; ++d)
        #pragma unroll
        for (int e = 0; e < 4; ++e)
          patch[ic][d][e] = ins[ic][ry + d][rx + e];
    float m = -1e30f;
    #pragma unroll
    for (int sy = 0; sy < 2; ++sy)
      #pragma unroll
      for (int sx = 0; sx < 2; ++sx) {
        float acc = b1s[oc];
        #pragma unroll
        for (int ic = 0; ic < 3; ++ic)
          #pragma unroll
          for (int ky = 0; ky < 3; ++ky)
            #pragma unroll
            for (int kx = 0; kx < 3; ++kx)
              acc += patch[ic][sy+ky][sx+kx] * w1s[(oc*3+ic)*9 + ky*3 + kx];
        m = fmaxf(m, acc);
      }
    // tanh monotonic: maxpool(tanh(.)) == tanh(maxpool(.))
    x1s[oc][ly][lx] = tanhf(m);
  }
  __syncthreads();

  // ---- stage B: pooled conv2 window [8][5][5] -> product with w3
  float prod = 0.0f;
  if (tid < 200) {
    int oc2 = tid / 25; int rem = tid - oc2*25; int j = rem / 5; int i5 = rem - j*5;
    float a00 = b2s[oc2], a01 = a00, a10 = a00, a11 = a00;
    for (int ic = 0; ic < 16; ++ic) {
      float p[4][4];
      #pragma unroll
      for (int d = 0; d < 4; ++d)
        #pragma unroll
        for (int e = 0; e < 4; ++e)
          p[d][e] = x1s[ic][2*j + d][2*i5 + e];
      #pragma unroll
      for (int ky = 0; ky < 3; ++ky)
        #pragma unroll
        for (int kx = 0; kx < 3; ++kx) {
          float wv = w2s[((oc2*16 + ic)*3 + ky)*3 + kx];
          a00 += p[ky  ][kx  ]*wv;
          a01 += p[ky  ][kx+1]*wv;
          a10 += p[ky+1][kx  ]*wv;
          a11 += p[ky+1][kx+1]*wv;
        }
    }
    float x2 = fmaxf(fmaxf(a00, a01), fmaxf(a10, a11));
    prod = x2 * w3s[tid];          // w3 index (oc2*5+j)*5+i5 == tid
  }
  red[tid] = prod;
  __syncthreads();

  // ---- stage C: reduce 200 products + bias -> sigmoid
  if (tid < 64) {
    float s = red[tid] + red[tid+64] + red[tid+128] + red[tid+192];
    #pragma unroll
    for (int off = 32; off > 0; off >>= 1) s += __shfl_down(s, off);
    if (tid == 0)
      cv[l] = 1.0f / (1.0f + expf(-(s + b3s)));
  }
}

// ---------------------------------------------------------------------------
extern "C" void kernel_launch(void* const* d_in, const int* in_sizes, int n_in,
                              void* d_out, int out_size, void* d_ws, size_t ws_size,
                              hipStream_t stream) {
  const float* inp = (const float*)d_in[0];
  const float* w1  = (const float*)d_in[1];
  const float* b1  = (const float*)d_in[2];
  const float* w2  = (const float*)d_in[3];
  const float* b2  = (const float*)d_in[4];
  const float* w3  = (const float*)d_in[5];
  const float* b3  = (const float*)d_in[6];
  const float* wl  = (const float*)d_in[7];
  const float* bl  = (const float*)d_in[8];
  // d_in[9..14] = wc1,bc1,wc2,bc2,wc3,bc3: dead (gate sigmoid <= 1 -> mask always False)

  float* out = (float*)d_out;

  hipLaunchKernelGGL(light_kernel, dim3(NBLK), dim3(256), 0, stream, inp, wl, bl, out);
  hipLaunchKernelGGL(gate_fused, dim3(NBLK), dim3(256), 0, stream,
                     inp, w1, b1, w2, b2, w3, b3, out + OUT_IMG);
}